// Round 7
// baseline (264.433 us; speedup 1.0000x reference)
//
#include <hip/hip_runtime.h>
#include <hip/hip_fp16.h>
#include <stdint.h>

typedef int i32x4 __attribute__((ext_vector_type(4)));
typedef int i32x16 __attribute__((ext_vector_type(16)));

#define BM 256
#define BN 256
#define BKB 64            // K-bytes per tile
#define NSLOT 4
#define SLOT_BYTES 32768  // A 16KB + B 16KB
#define THREADS 256

__device__ __forceinline__ void gload_lds16(const void* g, void* l) {
  __builtin_amdgcn_global_load_lds(
      (const __attribute__((address_space(1))) unsigned int*)g,
      (__attribute__((address_space(3))) unsigned int*)l, 16, 0, 0);
}

// ---------------- quantize x: fp32(fp16 values) -> int8, grid-stride --------
__global__ __launch_bounds__(256) void quant_x_kernel(
    const float* __restrict__ x, const float* __restrict__ deltap,
    const float* __restrict__ zpp, int8_t* __restrict__ q, int n16) {
  const float rdelta = 1.0f / deltap[0];
  const float zp = zpp[0];
  for (int i = blockIdx.x * blockDim.x + threadIdx.x; i < n16;
       i += gridDim.x * blockDim.x) {
    const float4* src = (const float4*)x + (size_t)i * 4;
    int packed[4];
#pragma unroll
    for (int g = 0; g < 4; ++g) {
      float4 v = src[g];
      float f0 = fminf(127.f, fmaxf(-128.f, rintf(fmaf(v.x, rdelta, zp))));
      float f1 = fminf(127.f, fmaxf(-128.f, rintf(fmaf(v.y, rdelta, zp))));
      float f2 = fminf(127.f, fmaxf(-128.f, rintf(fmaf(v.z, rdelta, zp))));
      float f3 = fminf(127.f, fmaxf(-128.f, rintf(fmaf(v.w, rdelta, zp))));
      int q0 = (int)f0 & 255, q1 = (int)f1 & 255, q2 = (int)f2 & 255, q3 = (int)f3 & 255;
      packed[g] = q0 | (q1 << 8) | (q2 << 16) | (q3 << 24);
    }
    ((int4*)q)[i] = make_int4(packed[0], packed[1], packed[2], packed[3]);
  }
}

// ---------------- pack W: int32 -> int8, 16 elems/thread --------------------
__global__ __launch_bounds__(256) void pack_w_kernel(
    const int* __restrict__ w, int8_t* __restrict__ wp, int n16) {
  int i = blockIdx.x * blockDim.x + threadIdx.x;
  if (i >= n16) return;
  const int4* src = (const int4*)w + (size_t)i * 4;
  int packed[4];
#pragma unroll
  for (int g = 0; g < 4; ++g) {
    int4 v = src[g];
    packed[g] = (v.x & 255) | ((v.y & 255) << 8) | ((v.z & 255) << 16) | ((v.w & 255) << 24);
  }
  ((int4*)wp)[i] = make_int4(packed[0], packed[1], packed[2], packed[3]);
}

// ---------------- int8 GEMM, 256x256 tile, 32x32x32 MFMA, reg-dbuf ----------
// 4 waves (2x2), per-wave 128x128 out, acc[4][4] i32x16 (256 VGPR).
// Register fragment double-buffer: ds_reads for tile t+1 issue BEFORE the
// MFMA cluster of tile t (which uses already-resident regs -> no lgkm wait
// on the critical path; reads retire under ~1200cy of MFMA).
// LDS: 4-slot rotation (128KB), depth-3 prefetch, vmcnt(8)/boundary (drains
// U(t+2) needed by next step's ds_reads). One barrier per tile.
// T2 chunk-XOR swizzle (r2-r6, 0 conflicts) + T1 XCD swizzle.
__global__ __launch_bounds__(THREADS, 1) void gemm_i8_kernel(
    const int8_t* __restrict__ Aq, const int8_t* __restrict__ Bw,
    const float* __restrict__ atwd, const float* __restrict__ zpws,
    const float* __restrict__ bias, float* __restrict__ out,
    int Mc, int Nc, int Kc) {
  __shared__ int8_t lds[NSLOT * SLOT_BYTES];

  // ---- T1 bijective XCD swizzle (nwg multiple of 8 here) ----
  const int nwg = gridDim.x;
  int bid = blockIdx.x;
  if ((nwg & 7) == 0) bid = (bid & 7) * (nwg >> 3) + (bid >> 3);
  const int nbn = Nc / BN;
  const int bm = bid / nbn;
  const int bn = bid % nbn;

  const int tid = threadIdx.x;
  const size_t K = (size_t)Kc;
  const int NT = Kc / BKB;

  // ---- staging: sweep = 256 thr x 16B = 4KB = 64 rows x 64B ----
  const int srow = tid >> 2;                        // 0..63
  const int lc = (tid & 3) ^ ((tid >> 3) & 3);      // inverse-swizzled chunk
  const int8_t* gA = Aq + ((size_t)(bm * BM + srow)) * K + lc * 16;
  const int8_t* gB = Bw + ((size_t)(bn * BN + srow)) * K + lc * 16;
  const size_t row64 = (size_t)64 * K;
  int8_t* ldst = &lds[tid * 16];

  auto stage = [&](int t, int slot) {   // 8 gloads: A 4x4KB, B 4x4KB
    int8_t* l = ldst + slot * SLOT_BYTES;
    const size_t koff = (size_t)t * BKB;
#pragma unroll
    for (int r = 0; r < 4; ++r)
      gload_lds16(gA + koff + r * row64, l + r * 4096);
#pragma unroll
    for (int r = 0; r < 4; ++r)
      gload_lds16(gB + koff + r * row64, l + 16384 + r * 4096);
  };

  // ---- fragment geometry: 4 waves 2x2, each 128x128; 32x32x32 frags ----
  const int lane = tid & 63;
  const int wave = tid >> 6;
  const int wr = wave >> 1;          // 0..1 -> 128 rows
  const int wc = wave & 1;           // 0..1 -> 128 cols
  const int fr32 = lane & 31;
  const int kh = lane >> 5;          // K-half within 32-elem step
  const int aRow = wr * 128 + fr32;
  const int bRow = wc * 128 + fr32;
  const int aSwz = (aRow >> 1) & 3;  // uniform across i (i*32 -> (>>1)&3 = 0)
  const int bSwz = (bRow >> 1) & 3;

  i32x4 fa[2][4][2], fb[2][4][2];   // [buf][frag][kstep], all literal-indexed
  i32x16 acc[4][4] = {};

#define READF(BUF, t)                                                         \
  {                                                                           \
    const int8_t* sA_ = &lds[((t) & 3) * SLOT_BYTES];                         \
    const int8_t* sB_ = sA_ + 16384;                                          \
    _Pragma("unroll") for (int i_ = 0; i_ < 4; ++i_)                          \
      _Pragma("unroll") for (int ks_ = 0; ks_ < 2; ++ks_)                     \
        fa[BUF][i_][ks_] = *(const i32x4*)&sA_[(aRow + i_ * 32) * 64 +        \
            (((ks_ * 2 + kh) ^ aSwz) << 4)];                                  \
    _Pragma("unroll") for (int j_ = 0; j_ < 4; ++j_)                          \
      _Pragma("unroll") for (int ks_ = 0; ks_ < 2; ++ks_)                     \
        fb[BUF][j_][ks_] = *(const i32x4*)&sB_[(bRow + j_ * 32) * 64 +        \
            (((ks_ * 2 + kh) ^ bSwz) << 4)];                                  \
  }

#define STEP(B0, B1, t)                                                       \
  {                                                                           \
    if ((t) + 1 < NT) READF(B1, (t) + 1);                                     \
    if ((t) + 3 < NT) stage((t) + 3, ((t) + 3) & 3);                          \
    _Pragma("unroll") for (int i_ = 0; i_ < 4; ++i_)                          \
      _Pragma("unroll") for (int j_ = 0; j_ < 4; ++j_) {                      \
        acc[i_][j_] = __builtin_amdgcn_mfma_i32_32x32x32_i8(                  \
            fa[B0][i_][0], fb[B0][j_][0], acc[i_][j_], 0, 0, 0);              \
        acc[i_][j_] = __builtin_amdgcn_mfma_i32_32x32x32_i8(                  \
            fa[B0][i_][1], fb[B0][j_][1], acc[i_][j_], 0, 0, 0);              \
      }                                                                       \
    if ((t) + 3 < NT) asm volatile("s_waitcnt vmcnt(8)" ::: "memory");        \
    else              asm volatile("s_waitcnt vmcnt(0)" ::: "memory");        \
    __builtin_amdgcn_s_barrier();                                             \
    __builtin_amdgcn_sched_barrier(0);                                        \
  }

  // ---- prologue: stage U(0..2); drain U(0),U(1); fill buf0 = frags(0) ----
  stage(0, 0);
  stage(1, 1);
  stage(2, 2);
  asm volatile("s_waitcnt vmcnt(8)" ::: "memory");
  __builtin_amdgcn_s_barrier();
  __builtin_amdgcn_sched_barrier(0);
  READF(0, 0);

  for (int t = 0; t < NT; t += 2) {
    STEP(0, 1, t);
    STEP(1, 0, t + 1);
  }
#undef STEP
#undef READF

  // ---- epilogue: 32x32 C/D: col=lane&31, row=(reg&3)+8*(reg>>2)+4*(lane>>5)
  const int cn0 = bn * BN + wc * 128 + fr32;
  float aw[4], zs[4], bs[4];
#pragma unroll
  for (int j = 0; j < 4; ++j) {
    aw[j] = atwd[cn0 + j * 32];
    zs[j] = zpws[cn0 + j * 32];
    bs[j] = bias[cn0 + j * 32];
  }
  const int rbase0 = bm * BM + wr * 128 + 4 * kh;
#pragma unroll
  for (int i = 0; i < 4; ++i) {
#pragma unroll
    for (int reg = 0; reg < 16; ++reg) {
      const int rloc = (reg & 3) + 8 * (reg >> 2);
      const size_t rbase = (size_t)(rbase0 + i * 32 + rloc) * (size_t)Nc;
#pragma unroll
      for (int j = 0; j < 4; ++j) {
        float v = (float)acc[i][j][reg] * aw[j] - zs[j] + bs[j];
        v = __half2float(__float2half(v));  // match fp16 output rounding
        out[rbase + cn0 + j * 32] = v;
      }
    }
  }
}

extern "C" void kernel_launch(void* const* d_in, const int* in_sizes, int n_in,
                              void* d_out, int out_size, void* d_ws, size_t ws_size,
                              hipStream_t stream) {
  const float* x         = (const float*)d_in[0];
  const float* act_delta = (const float*)d_in[1];
  const float* act_zp    = (const float*)d_in[2];
  const float* zpws      = (const float*)d_in[3];
  const float* atwd      = (const float*)d_in[4];
  const float* bias      = (const float*)d_in[5];
  const int*   w32       = (const int*)d_in[6];
  float* out = (float*)d_out;

  const int N = in_sizes[5];
  const int K = in_sizes[6] / N;
  const int M = in_sizes[0] / K;

  int8_t* q  = (int8_t*)d_ws;               // M*K bytes
  int8_t* wp = q + (size_t)M * K;           // N*K bytes

  {
    int n16 = (M * K) / 16;
    int grid = (n16 + 255) / 256;
    if (grid > 2048) grid = 2048;
    quant_x_kernel<<<grid, 256, 0, stream>>>(x, act_delta, act_zp, q, n16);
  }
  {
    int n16 = (N * K) / 16;
    pack_w_kernel<<<(n16 + 255) / 256, 256, 0, stream>>>(w32, wp, n16);
  }
  {
    dim3 grid((M / BM) * (N / BN));
    gemm_i8_kernel<<<grid, THREADS, 0, stream>>>(q, wp, atwd, zpws, bias, out, M, N, K);
  }
}

// Round 8
// 245.782 us; speedup vs baseline: 1.0759x; 1.0759x over previous
//
#include <hip/hip_runtime.h>
#include <hip/hip_fp16.h>
#include <stdint.h>

typedef int i32x4 __attribute__((ext_vector_type(4)));

#define BM 256
#define BN 256
#define BKB 128           // K-bytes (= int8 elems) per tile (m201 byte geometry)
#define SLOT 65536        // A 32KB + B 32KB per slot, 2 slots = 128KB
#define THREADS 512

__device__ __forceinline__ void gload_lds16(const void* g, void* l) {
  __builtin_amdgcn_global_load_lds(
      (const __attribute__((address_space(1))) unsigned int*)g,
      (__attribute__((address_space(3))) unsigned int*)l, 16, 0, 0);
}

// ---------------- quantize x: fp32(fp16 values) -> int8, grid-stride --------
__global__ __launch_bounds__(256) void quant_x_kernel(
    const float* __restrict__ x, const float* __restrict__ deltap,
    const float* __restrict__ zpp, int8_t* __restrict__ q, int n16) {
  const float rdelta = 1.0f / deltap[0];
  const float zp = zpp[0];
  for (int i = blockIdx.x * blockDim.x + threadIdx.x; i < n16;
       i += gridDim.x * blockDim.x) {
    const float4* src = (const float4*)x + (size_t)i * 4;
    int packed[4];
#pragma unroll
    for (int g = 0; g < 4; ++g) {
      float4 v = src[g];
      float f0 = fminf(127.f, fmaxf(-128.f, rintf(fmaf(v.x, rdelta, zp))));
      float f1 = fminf(127.f, fmaxf(-128.f, rintf(fmaf(v.y, rdelta, zp))));
      float f2 = fminf(127.f, fmaxf(-128.f, rintf(fmaf(v.z, rdelta, zp))));
      float f3 = fminf(127.f, fmaxf(-128.f, rintf(fmaf(v.w, rdelta, zp))));
      int q0 = (int)f0 & 255, q1 = (int)f1 & 255, q2 = (int)f2 & 255, q3 = (int)f3 & 255;
      packed[g] = q0 | (q1 << 8) | (q2 << 16) | (q3 << 24);
    }
    ((int4*)q)[i] = make_int4(packed[0], packed[1], packed[2], packed[3]);
  }
}

// ---------------- pack W: int32 -> int8, 16 elems/thread --------------------
__global__ __launch_bounds__(256) void pack_w_kernel(
    const int* __restrict__ w, int8_t* __restrict__ wp, int n16) {
  int i = blockIdx.x * blockDim.x + threadIdx.x;
  if (i >= n16) return;
  const int4* src = (const int4*)w + (size_t)i * 4;
  int packed[4];
#pragma unroll
  for (int g = 0; g < 4; ++g) {
    int4 v = src[g];
    packed[g] = (v.x & 255) | ((v.y & 255) << 8) | ((v.z & 255) << 16) | ((v.w & 255) << 24);
  }
  ((int4*)wp)[i] = make_int4(packed[0], packed[1], packed[2], packed[3]);
}

// ---------------- int8 GEMM, 256x256 tile, BK=128B, one barrier/tile --------
// 8 waves (2M x 4N), per-wave 128x64 out, acc[8][4] i32x4 (AGPR).
// Per tile: {24 ds_read_b128 | 64 MFMA/wave | 8 gloads for U(t+1)} with the
// round-4-proven compiler-scheduled interior; 2614 MFMA-cy/tile vs the
// structure-invariant ~3300-cy tile wall -> 2x ops per wall vs BK=64.
// LDS: 2 slots x 64KB double buffer. vmcnt(0)+barrier at tile end only.
// 8-chunk XOR swizzle: storage chunk = logical ^ (row&7); inverse applied on
// global source (linear gload_lds dest, rule #21). T1 XCD swizzle.
__global__ __launch_bounds__(THREADS, 2) void gemm_i8_kernel(
    const int8_t* __restrict__ Aq, const int8_t* __restrict__ Bw,
    const float* __restrict__ atwd, const float* __restrict__ zpws,
    const float* __restrict__ bias, float* __restrict__ out,
    int Mc, int Nc, int Kc) {
  __shared__ int8_t lds[2 * SLOT];

  // ---- T1 bijective XCD swizzle (nwg multiple of 8 here) ----
  const int nwg = gridDim.x;
  int bid = blockIdx.x;
  if ((nwg & 7) == 0) bid = (bid & 7) * (nwg >> 3) + (bid >> 3);
  const int nbn = Nc / BN;
  const int bm = bid / nbn;
  const int bn = bid % nbn;

  const int tid = threadIdx.x;
  const size_t K = (size_t)Kc;
  const int NT = Kc / BKB;

  // ---- staging: sweep = 512 thr x 16B = 8KB = 64 rows x 128B ----
  const int srow = tid >> 3;                        // 0..63
  const int cs = tid & 7;                           // storage chunk
  const int cl = cs ^ (srow & 7);                   // inverse-swizzled source
  const int8_t* gA = Aq + ((size_t)(bm * BM + srow)) * K + cl * 16;
  const int8_t* gB = Bw + ((size_t)(bn * BN + srow)) * K + cl * 16;
  const size_t row64 = (size_t)64 * K;
  int8_t* ldst = &lds[tid * 16];

  auto stage = [&](int t, int slot) {   // 8 gloads: A 4x8KB, B 4x8KB
    int8_t* l = ldst + slot * SLOT;
    const size_t koff = (size_t)t * BKB;
#pragma unroll
    for (int r = 0; r < 4; ++r)
      gload_lds16(gA + koff + r * row64, l + r * 8192);
#pragma unroll
    for (int r = 0; r < 4; ++r)
      gload_lds16(gB + koff + r * row64, l + 32768 + r * 8192);
  };

  // ---- fragment geometry: 8 waves 2x4, per-wave 128x64 ----
  const int lane = tid & 63;
  const int wave = tid >> 6;
  const int wr = wave >> 2;          // 0..1 -> 128 rows
  const int wc = wave & 3;           // 0..3 -> 64 cols
  const int fr = lane & 15;
  const int kc = lane >> 4;          // 16B chunk within K-half
  const int swz = fr & 7;
  const int aRow = wr * 128 + fr;
  const int bRow = wc * 64 + fr;

  i32x4 acc[8][4] = {};

  // ---- prologue ----
  stage(0, 0);
  asm volatile("s_waitcnt vmcnt(0)" ::: "memory");
  __builtin_amdgcn_s_barrier();
  __builtin_amdgcn_sched_barrier(0);

  for (int t = 0; t < NT; ++t) {
    const int8_t* sA = &lds[(t & 1) * SLOT];
    const int8_t* sB = sA + 32768;

    i32x4 af[8][2], bf[4][2];
#pragma unroll
    for (int ks = 0; ks < 2; ++ks) {
      const int co = ((ks * 4 + kc) ^ swz) << 4;   // swizzled byte offset
#pragma unroll
      for (int j = 0; j < 4; ++j)
        bf[j][ks] = *(const i32x4*)&sB[(bRow + j * 16) * 128 + co];
#pragma unroll
      for (int i = 0; i < 8; ++i)
        af[i][ks] = *(const i32x4*)&sA[(aRow + ((i & 3) * 16) + ((i >> 2) * 64)) * 128 + co];
    }

    if (t + 1 < NT) stage(t + 1, (t + 1) & 1);

#pragma unroll
    for (int ks = 0; ks < 2; ++ks)
#pragma unroll
      for (int i = 0; i < 8; ++i)
#pragma unroll
        for (int j = 0; j < 4; ++j)
          acc[i][j] = __builtin_amdgcn_mfma_i32_16x16x64_i8(
              af[((i >> 2) * 4) + (i & 3)][ks], bf[j][ks], acc[i][j], 0, 0, 0);

    // ---- tile boundary: U(t+1) landed, collective barrier ----
    if (t < NT - 1) {
      asm volatile("s_waitcnt vmcnt(0)" ::: "memory");
      __builtin_amdgcn_s_barrier();
      __builtin_amdgcn_sched_barrier(0);
    }
  }

  // ---- epilogue: C/D col=lane&15, row=(lane>>4)*4+reg; j-innermost
  // (4 consecutive j-stores cover 4x16 floats of one row).
  // af index map: mi = (i>>2)*4+(i&3) covers rows mi*16 within the wave's
  // 128-row strip: mi 0..3 -> rows 0..63, mi 4..7 -> rows 64..127.
  const int r4 = (lane >> 4) << 2;
  const int cn0 = bn * BN + wc * 64 + fr;
  float aw4[4], zs4[4], bs4[4];
#pragma unroll
  for (int j = 0; j < 4; ++j) {
    aw4[j] = atwd[cn0 + j * 16];
    zs4[j] = zpws[cn0 + j * 16];
    bs4[j] = bias[cn0 + j * 16];
  }
#pragma unroll
  for (int i = 0; i < 8; ++i) {
    const int mrow = ((i & 3) * 16) + ((i >> 2) * 64);
#pragma unroll
    for (int r = 0; r < 4; ++r) {
      const size_t rbase = (size_t)(bm * BM + wr * 128 + mrow + r4 + r) * (size_t)Nc;
#pragma unroll
      for (int j = 0; j < 4; ++j) {
        float v = (float)acc[i][j][r] * aw4[j] - zs4[j] + bs4[j];
        v = __half2float(__float2half(v));  // match fp16 output rounding
        out[rbase + cn0 + j * 16] = v;
      }
    }
  }
}

extern "C" void kernel_launch(void* const* d_in, const int* in_sizes, int n_in,
                              void* d_out, int out_size, void* d_ws, size_t ws_size,
                              hipStream_t stream) {
  const float* x         = (const float*)d_in[0];
  const float* act_delta = (const float*)d_in[1];
  const float* act_zp    = (const float*)d_in[2];
  const float* zpws      = (const float*)d_in[3];
  const float* atwd      = (const float*)d_in[4];
  const float* bias      = (const float*)d_in[5];
  const int*   w32       = (const int*)d_in[6];
  float* out = (float*)d_out;

  const int N = in_sizes[5];
  const int K = in_sizes[6] / N;
  const int M = in_sizes[0] / K;

  int8_t* q  = (int8_t*)d_ws;               // M*K bytes
  int8_t* wp = q + (size_t)M * K;           // N*K bytes

  {
    int n16 = (M * K) / 16;
    int grid = (n16 + 255) / 256;
    if (grid > 2048) grid = 2048;
    quant_x_kernel<<<grid, 256, 0, stream>>>(x, act_delta, act_zp, q, n16);
  }
  {
    int n16 = (N * K) / 16;
    pack_w_kernel<<<(n16 + 255) / 256, 256, 0, stream>>>(w32, wp, n16);
  }
  {
    dim3 grid((M / BM) * (N / BN));
    gemm_i8_kernel<<<grid, THREADS, 0, stream>>>(q, wp, atwd, zpws, bias, out, M, N, K);
  }
}